// Round 7
// baseline (85.808 us; speedup 1.0000x reference)
//
#include <hip/hip_runtime.h>
#include <math.h>

#define HW     224
#define IMG    (HW * HW)        // 50176
#define OW     223
#define FLAT   (OW * OW)        // 49729
#define NB     1024
#define NGRP   (OW * 56)        // 12488 groups of 4 positions
#define EWPK   (NGRP * 16)      // packed embed_w floats
#define NI     4                // images per block (one per wave)
#define NSLICE 8                // row slices
#define PPB    7                // panels per block (NSLICE*PPB*RPP = 224 >= 223 rows)
#define RPP    4                // position rows per panel
#define GPP    (RPP * 56)       // 224 groups per panel
#define RING   9                // LDS x-row ring (5 live + 4 staging)
#define ROWF   240              // padded LDS row length in floats (224 + 16 pad)

typedef unsigned int u32;
__device__ __forceinline__ void gload16(const float* gp, float* lp) {
    __builtin_amdgcn_global_load_lds(
        (const __attribute__((address_space(1))) u32*)gp,
        (__attribute__((address_space(3))) u32*)lp, 16, 0, 0);
}

// ---------------------------------------------------------------------------
// Kernel 0: repack embed_w [4][FLAT] -> ew_pack[g][c][4]; zero-fill the
// invalid col-223 slot (the .w of group jg==55).
// ---------------------------------------------------------------------------
__global__ __launch_bounds__(256) void pack_ew_kernel(
    const float* __restrict__ embed_w, float* __restrict__ ew_pack)
{
    int idx = blockIdx.x * 256 + threadIdx.x;
    if (idx >= NGRP * 4) return;
    int g = idx >> 2;
    int c = idx & 3;
    int i  = g / 56;
    int j0 = (g - i * 56) * 4;
    const float* src = embed_w + (size_t)c * FLAT + (size_t)i * OW + j0;
    float v0 = src[0];
    float v1 = (j0 + 1 < OW) ? src[1] : 0.f;
    float v2 = (j0 + 2 < OW) ? src[2] : 0.f;
    float v3 = (j0 + 3 < OW) ? src[3] : 0.f;
    ((float4*)(ew_pack + (size_t)g * 16 + c * 4))[0] = make_float4(v0, v1, v2, v3);
}

// ---------------------------------------------------------------------------
// Kernel 1: fused conv+sigmoid+embed, global_load_lds double-buffered.
// grid = 256 image-sets x 8 slices. Each block: 4 images (wave=image),
// 7 panels x 4 position rows x full width. x rows live in a 9-slot LDS ring
// (each x row staged once); ew panel staged plane-transposed, double-buffered.
// Per iter: issue stage(p+1) -> compute(p) from LDS -> vmcnt(0)+barrier.
// ---------------------------------------------------------------------------
__global__ __launch_bounds__(256, 2) void conv_embed_lds(
    const float* __restrict__ x, const float* __restrict__ conv_w,
    const float* __restrict__ conv_b, const float* __restrict__ ew_pack,
    float* __restrict__ partial)   // [NSLICE][NB][4]
{
    __shared__ float x_lds[NI * RING * ROWF];      // 34560 B
    __shared__ float ew_lds[2][4][GPP * 4];        // 28672 B  (plane-major)

    const int blk   = blockIdx.x;
    const int slice = blk & (NSLICE - 1);
    const int b0    = (blk >> 3) * NI;
    const int tid   = threadIdx.x;
    const int wid   = tid >> 6;       // wave id == image index
    const int lane  = tid & 63;
    const int R0    = slice * (PPB * RPP);         // first position row

    const float w00 = conv_w[0], w01 = conv_w[1];
    const float w10 = conv_w[2], w11 = conv_w[3];
    const float cb  = conv_b[0];

    // zero the pad columns (224..239) of every ring row once
    for (int z = tid; z < NI * RING * 16; z += 256) {
        int rowi = z >> 4, ci = z & 15;
        x_lds[rowi * ROWF + 224 + ci] = 0.f;
    }

    // ---- prologue: stage x local rows 0..4 (all 4 images) + ew panel 0 ----
    for (int id = wid; id < 20; id += 4) {         // wave-uniform call loop
        int im2 = id / 5, k = id % 5;
        int A = R0 + k; A = (A > 223) ? 223 : A;
        if (lane < 56) {
            const float* gp = x + ((size_t)(b0 + im2) * IMG + (size_t)A * HW) + lane * 4;
            gload16(gp, &x_lds[(im2 * RING + k) * ROWF]);
        }
    }
    {
        const int gs = R0 * 56;
        for (int id = wid; id < 16; id += 4) {
            int j = id >> 2, n = id & 3;
            int idx = n * 64 + lane;
            if (idx < GPP) {
                const float* gp = ew_pack + (size_t)(gs + idx) * 16 + j * 4;
                gload16(gp, &ew_lds[0][j][n * 256]);
            }
        }
    }
    asm volatile("s_waitcnt vmcnt(0)" ::: "memory");
    __syncthreads();

    float a0 = 0.f, a1 = 0.f, a2 = 0.f, a3 = 0.f;  // 4 channels, image = wid
    const float* xb_img = &x_lds[wid * RING * ROWF];

    for (int p = 0; p < PPB; ++p) {
        // ---- issue stage for panel p+1 ----
        if (p < PPB - 1) {
            for (int id = wid; id < 16; id += 4) { // x rows local 4p+5..4p+8
                int im2 = id >> 2, k = id & 3;
                int lr = 4 * p + 5 + k;
                int A = R0 + lr; A = (A > 223) ? 223 : A;
                int slot = lr % RING;
                if (lane < 56) {
                    const float* gp = x + ((size_t)(b0 + im2) * IMG + (size_t)A * HW) + lane * 4;
                    gload16(gp, &x_lds[(im2 * RING + slot) * ROWF]);
                }
            }
            const int gs = (R0 + 4 * (p + 1)) * 56;
            const int pb = (p + 1) & 1;
            for (int id = wid; id < 16; id += 4) {
                int j = id >> 2, n = id & 3;
                int idx = n * 64 + lane;
                if (idx < GPP) {
                    const float* gp = ew_pack + (size_t)(gs + idx) * 16 + j * 4;
                    gload16(gp, &ew_lds[pb][j][n * 256]);
                }
            }
        }

        // ---- compute panel p from LDS ----
        const int pb = p & 1;
        const int s0 = (4 * p) % RING;
        #pragma unroll
        for (int kk = 0; kk < 4; ++kk) {
            const int idx = kk * 64 + lane;
            const int r  = idx / 56;
            const int c  = idx - r * 56;
            const int PR = R0 + 4 * p + r;
            if (idx < GPP && PR <= 222) {
                int st = s0 + r;   st  -= (st  >= RING) ? RING : 0;
                int st1 = st + 1;  st1 -= (st1 >= RING) ? RING : 0;
                const float* rt = xb_img + st  * ROWF + c * 4;
                const float* rb = xb_img + st1 * ROWF + c * 4;
                float4 t  = *(const float4*)rt;  float te = rt[4];
                float4 bt = *(const float4*)rb;  float be = rb[4];
                float4 e0 = *(const float4*)&ew_lds[pb][0][idx * 4];
                float4 e1 = *(const float4*)&ew_lds[pb][1][idx * 4];
                float4 e2 = *(const float4*)&ew_lds[pb][2][idx * 4];
                float4 e3 = *(const float4*)&ew_lds[pb][3][idx * 4];
                float z0 = w00 * t.x + w01 * t.y + w10 * bt.x + w11 * bt.y + cb;
                float z1 = w00 * t.y + w01 * t.z + w10 * bt.y + w11 * bt.z + cb;
                float z2 = w00 * t.z + w01 * t.w + w10 * bt.z + w11 * bt.w + cb;
                float z3 = w00 * t.w + w01 * te  + w10 * bt.w + w11 * be  + cb;
                float s0f = __builtin_amdgcn_rcpf(1.0f + __expf(-z0));
                float s1f = __builtin_amdgcn_rcpf(1.0f + __expf(-z1));
                float s2f = __builtin_amdgcn_rcpf(1.0f + __expf(-z2));
                float s3f = __builtin_amdgcn_rcpf(1.0f + __expf(-z3));
                a0 += s0f * e0.x + s1f * e0.y + s2f * e0.z + s3f * e0.w;
                a1 += s0f * e1.x + s1f * e1.y + s2f * e1.z + s3f * e1.w;
                a2 += s0f * e2.x + s1f * e2.y + s2f * e2.z + s3f * e2.w;
                a3 += s0f * e3.x + s1f * e3.y + s2f * e3.z + s3f * e3.w;
            }
        }

        asm volatile("s_waitcnt vmcnt(0)" ::: "memory");
        __syncthreads();
    }

    // ---- wave reduction; lane 0 of each wave writes its image's partial ----
    #pragma unroll
    for (int off = 32; off > 0; off >>= 1) {
        a0 += __shfl_down(a0, off, 64);
        a1 += __shfl_down(a1, off, 64);
        a2 += __shfl_down(a2, off, 64);
        a3 += __shfl_down(a3, off, 64);
    }
    if (lane == 0)
        ((float4*)(partial + ((size_t)slice * NB + b0 + wid) * 4))[0] =
            make_float4(a0, a1, a2, a3);
}

// ---------------------------------------------------------------------------
// Fallback (round-1 style) if ws too small.
// ---------------------------------------------------------------------------
__global__ __launch_bounds__(256) void conv_embed_kernel(
    const float* __restrict__ x, const float* __restrict__ conv_w,
    const float* __restrict__ conv_b, const float* __restrict__ embed_w,
    const float* __restrict__ embed_b, float* __restrict__ embedded)
{
    const int b   = blockIdx.x;
    const int tid = threadIdx.x;
    const float w00 = conv_w[0], w01 = conv_w[1];
    const float w10 = conv_w[2], w11 = conv_w[3];
    const float cb  = conv_b[0];
    const float* __restrict__ xb  = x + (size_t)b * IMG;
    const float* __restrict__ ew0 = embed_w;
    const float* __restrict__ ew1 = embed_w + FLAT;
    const float* __restrict__ ew2 = embed_w + 2 * FLAT;
    const float* __restrict__ ew3 = embed_w + 3 * FLAT;
    float a0 = 0.f, a1 = 0.f, a2 = 0.f, a3 = 0.f;
    for (int p = tid; p < FLAT; p += 256) {
        unsigned up = (unsigned)p;
        unsigned i  = up / 223u;
        unsigned j  = up - i * 223u;
        const float* xr = xb + i * HW + j;
        float z = w00 * xr[0] + w01 * xr[1] + w10 * xr[HW] + w11 * xr[HW + 1] + cb;
        float s = 1.0f / (1.0f + __expf(-z));
        a0 += s * ew0[p]; a1 += s * ew1[p]; a2 += s * ew2[p]; a3 += s * ew3[p];
    }
    #pragma unroll
    for (int off = 32; off > 0; off >>= 1) {
        a0 += __shfl_down(a0, off, 64);
        a1 += __shfl_down(a1, off, 64);
        a2 += __shfl_down(a2, off, 64);
        a3 += __shfl_down(a3, off, 64);
    }
    __shared__ float red[4][4];
    const int wid  = tid >> 6;
    const int lane = tid & 63;
    if (lane == 0) { red[wid][0]=a0; red[wid][1]=a1; red[wid][2]=a2; red[wid][3]=a3; }
    __syncthreads();
    if (tid == 0) {
        float r0 = red[0][0]+red[1][0]+red[2][0]+red[3][0]+embed_b[0];
        float r1 = red[0][1]+red[1][1]+red[2][1]+red[3][1]+embed_b[1];
        float r2 = red[0][2]+red[1][2]+red[2][2]+red[3][2]+embed_b[2];
        float r3 = red[0][3]+red[1][3]+red[2][3]+red[3][3]+embed_b[3];
        ((float4*)(embedded + (size_t)b * 4))[0] = make_float4(r0, r1, r2, r3);
    }
}

// ---------------------------------------------------------------------------
// Kernel 2: sum NSLICE partials (+bias) -> embedded, then q/k projections
// ---------------------------------------------------------------------------
__global__ __launch_bounds__(256) void qk_reduce_kernel(
    const float* __restrict__ partial, const float* __restrict__ embed_b,
    const float* __restrict__ rot, const float* __restrict__ ent,
    float* __restrict__ embedded, float* __restrict__ q, float* __restrict__ k)
{
    int b = blockIdx.x * 256 + threadIdx.x;
    if (b >= NB) return;
    float r0 = embed_b[0], r1 = embed_b[1], r2 = embed_b[2], r3 = embed_b[3];
    #pragma unroll
    for (int s = 0; s < NSLICE; ++s) {
        float4 p = ((const float4*)partial)[(size_t)s * NB + b];
        r0 += p.x; r1 += p.y; r2 += p.z; r3 += p.w;
    }
    float4 ev = make_float4(r0, r1, r2, r3);
    ((float4*)embedded)[b] = ev;
    float qv[4], kv[4];
    #pragma unroll
    for (int c = 0; c < 4; ++c) {
        qv[c] = ev.x * rot[0*4+c] + ev.y * rot[1*4+c] + ev.z * rot[2*4+c] + ev.w * rot[3*4+c];
        kv[c] = ev.x * ent[0*4+c] + ev.y * ent[1*4+c] + ev.z * ent[2*4+c] + ev.w * ent[3*4+c];
    }
    ((float4*)q)[b] = make_float4(qv[0], qv[1], qv[2], qv[3]);
    ((float4*)k)[b] = make_float4(kv[0], kv[1], kv[2], kv[3]);
}

__global__ __launch_bounds__(256) void qk_kernel(
    const float* __restrict__ embedded, const float* __restrict__ rot,
    const float* __restrict__ ent, float* __restrict__ q, float* __restrict__ k)
{
    int b = blockIdx.x * 256 + threadIdx.x;
    if (b >= NB) return;
    float4 ev = ((const float4*)embedded)[b];
    float qv[4], kv[4];
    #pragma unroll
    for (int c = 0; c < 4; ++c) {
        qv[c] = ev.x * rot[0*4+c] + ev.y * rot[1*4+c] + ev.z * rot[2*4+c] + ev.w * rot[3*4+c];
        kv[c] = ev.x * ent[0*4+c] + ev.y * ent[1*4+c] + ev.z * ent[2*4+c] + ev.w * ent[3*4+c];
    }
    ((float4*)q)[b] = make_float4(qv[0], qv[1], qv[2], qv[3]);
    ((float4*)k)[b] = make_float4(kv[0], kv[1], kv[2], kv[3]);
}

// ---------------------------------------------------------------------------
// Kernel 3: per-row softmax attention + mean + sigmoid -> out [NB, 2]
// ---------------------------------------------------------------------------
__global__ __launch_bounds__(256) void attn_kernel(
    const float* __restrict__ embedded, const float* __restrict__ q,
    const float* __restrict__ k, float* __restrict__ out)
{
    __shared__ float4 k_lds[NB];
    __shared__ float4 e_lds[NB];
    const int r   = blockIdx.x;
    const int tid = threadIdx.x;

    for (int c = tid; c < NB; c += 256) {
        k_lds[c] = ((const float4*)k)[c];
        e_lds[c] = ((const float4*)embedded)[c];
    }
    __syncthreads();

    const float4 qr = ((const float4*)q)[r];

    float m = -INFINITY, l = 0.f;
    float a0 = 0.f, a1 = 0.f, a2 = 0.f, a3 = 0.f;

    for (int c = tid; c < NB; c += 256) {
        float4 kc = k_lds[c];
        float s = 0.5f * (qr.x * kc.x + qr.y * kc.y + qr.z * kc.z + qr.w * kc.w);
        float mn    = fmaxf(m, s);
        float scale = __expf(m - mn);
        float p     = __expf(s - mn);
        float4 ec = e_lds[c];
        l  = l  * scale + p;
        a0 = a0 * scale + p * ec.x;
        a1 = a1 * scale + p * ec.y;
        a2 = a2 * scale + p * ec.z;
        a3 = a3 * scale + p * ec.w;
        m = mn;
    }

    #pragma unroll
    for (int off = 32; off > 0; off >>= 1) {
        float m2 = __shfl_down(m,  off, 64);
        float l2 = __shfl_down(l,  off, 64);
        float b0 = __shfl_down(a0, off, 64);
        float b1 = __shfl_down(a1, off, 64);
        float b2 = __shfl_down(a2, off, 64);
        float b3 = __shfl_down(a3, off, 64);
        float mn = fmaxf(m, m2);
        float s1 = __expf(m - mn), s2 = __expf(m2 - mn);
        l  = l  * s1 + l2 * s2;
        a0 = a0 * s1 + b0 * s2;
        a1 = a1 * s1 + b1 * s2;
        a2 = a2 * s1 + b2 * s2;
        a3 = a3 * s1 + b3 * s2;
        m = mn;
    }

    __shared__ float wred[4][6];
    const int wid  = tid >> 6;
    const int lane = tid & 63;
    if (lane == 0) {
        wred[wid][0] = m;  wred[wid][1] = l;
        wred[wid][2] = a0; wred[wid][3] = a1;
        wred[wid][4] = a2; wred[wid][5] = a3;
    }
    __syncthreads();
    if (tid == 0) {
        float M = wred[0][0], L = wred[0][1];
        float A0 = wred[0][2], A1 = wred[0][3], A2 = wred[0][4], A3 = wred[0][5];
        #pragma unroll
        for (int w = 1; w < 4; ++w) {
            float m2 = wred[w][0];
            float mn = fmaxf(M, m2);
            float s1 = __expf(M - mn), s2 = __expf(m2 - mn);
            L  = L  * s1 + wred[w][1] * s2;
            A0 = A0 * s1 + wred[w][2] * s2;
            A1 = A1 * s1 + wred[w][3] * s2;
            A2 = A2 * s1 + wred[w][4] * s2;
            A3 = A3 * s1 + wred[w][5] * s2;
            M = mn;
        }
        float mean = (A0 + A1 + A2 + A3) / (4.0f * L);
        float prob = 1.0f / (1.0f + __expf(-mean));
        out[r * 2 + 0] = prob;
        out[r * 2 + 1] = 1.0f - prob;
    }
}

// ---------------------------------------------------------------------------
extern "C" void kernel_launch(void* const* d_in, const int* in_sizes, int n_in,
                              void* d_out, int out_size, void* d_ws, size_t ws_size,
                              hipStream_t stream) {
    const float* x       = (const float*)d_in[0];
    const float* conv_w  = (const float*)d_in[1];
    const float* conv_b  = (const float*)d_in[2];
    const float* embed_w = (const float*)d_in[3];
    const float* embed_b = (const float*)d_in[4];
    const float* rot     = (const float*)d_in[5];
    const float* ent     = (const float*)d_in[6];
    float* out = (float*)d_out;

    float* partial  = (float*)d_ws;                 // NSLICE*NB*4 floats
    float* embedded = partial + NSLICE * NB * 4;    // NB*4
    float* q        = embedded + NB * 4;            // NB*4
    float* k        = q + NB * 4;                   // NB*4
    float* ew_pack  = k + NB * 4;                   // EWPK floats (+896 slack)

    // slack: ew staging for the (guarded-out) row-223 panel reads up to
    // group 12543 -> 896 floats past EWPK; must stay inside ws.
    const size_t need = (size_t)(NSLICE * NB * 4 + NB * 12 + EWPK + 1024) * sizeof(float);

    if (ws_size >= need) {
        pack_ew_kernel<<<(NGRP * 4 + 255) / 256, 256, 0, stream>>>(embed_w, ew_pack);
        conv_embed_lds<<<(NB / NI) * NSLICE, 256, 0, stream>>>(x, conv_w, conv_b,
                                                               ew_pack, partial);
        qk_reduce_kernel<<<NB / 256, 256, 0, stream>>>(partial, embed_b, rot, ent,
                                                       embedded, q, k);
    } else {
        conv_embed_kernel<<<NB, 256, 0, stream>>>(x, conv_w, conv_b, embed_w,
                                                  embed_b, embedded);
        qk_kernel<<<NB / 256, 256, 0, stream>>>(embedded, rot, ent, q, k);
    }
    attn_kernel<<<NB, 256, 0, stream>>>(embedded, q, k, out);
}

// Round 8
// 60.779 us; speedup vs baseline: 1.4118x; 1.4118x over previous
//
#include <hip/hip_runtime.h>
#include <math.h>

#define HW    224
#define IMG   (HW * HW)        // 50176
#define OW    223
#define FLAT  (OW * OW)        // 49729
#define NB    1024
#define NGRP  (OW * 56)        // 12488 groups of 4 positions
#define EWPK  (NGRP * 16)      // packed embed_w floats
#define NCH   8                // row chunks (28,28,...,27)
#define RPC   28

// ---------------------------------------------------------------------------
// Kernel 0: repack embed_w [4][FLAT] -> ew_pack[g][c][4], g = r*56 + cg,
// zero-filled where col >= 223 (the .w slot of col-group 55). This zero is
// what makes all edge handling in the conv kernel free.
// ---------------------------------------------------------------------------
__global__ __launch_bounds__(256) void pack_ew_kernel(
    const float* __restrict__ embed_w, float* __restrict__ ew_pack)
{
    int idx = blockIdx.x * 256 + threadIdx.x;
    if (idx >= NGRP * 4) return;
    int g = idx >> 2;
    int c = idx & 3;
    int i  = g / 56;
    int j0 = (g - i * 56) * 4;
    const float* src = embed_w + (size_t)c * FLAT + (size_t)i * OW + j0;
    float v0 = src[0];
    float v1 = (j0 + 1 < OW) ? src[1] : 0.f;
    float v2 = (j0 + 2 < OW) ? src[2] : 0.f;
    float v3 = (j0 + 3 < OW) ? src[3] : 0.f;
    ((float4*)(ew_pack + (size_t)g * 16 + c * 4))[0] = make_float4(v0, v1, v2, v3);
}

// ---------------------------------------------------------------------------
// Kernel 1: fused conv+sigmoid+embed, affine row-streaming.
// Block = (row chunk, 8 images); wave = 2 images, lane = col-group.
// Per iteration (one output row): 2 new x rows (bottom) + 4 ew f4, all
// addresses advance by constants; top row reused from registers; te/be via
// __shfl_down from the neighbor lane. No divisions, no branches in the body.
// Lanes 56-63 load clamped col 220 (always in-bounds) and are zeroed before
// the final reduction; group 55's .w==0 in ew_pack annihilates the invalid
// col-223 contribution.
// ---------------------------------------------------------------------------
#define CONV4(T, BT, TE, BE, A0, A1, A2, A3)                                   \
    {                                                                          \
        float z0 = w00 * T.x + w01 * T.y + w10 * BT.x + w11 * BT.y + cb;       \
        float z1 = w00 * T.y + w01 * T.z + w10 * BT.y + w11 * BT.z + cb;       \
        float z2 = w00 * T.z + w01 * T.w + w10 * BT.z + w11 * BT.w + cb;       \
        float z3 = w00 * T.w + w01 * TE  + w10 * BT.w + w11 * BE  + cb;        \
        float s0 = __builtin_amdgcn_rcpf(1.0f + __expf(-z0));                  \
        float s1 = __builtin_amdgcn_rcpf(1.0f + __expf(-z1));                  \
        float s2 = __builtin_amdgcn_rcpf(1.0f + __expf(-z2));                  \
        float s3 = __builtin_amdgcn_rcpf(1.0f + __expf(-z3));                  \
        A0 += s0 * e0.x + s1 * e0.y + s2 * e0.z + s3 * e0.w;                   \
        A1 += s0 * e1.x + s1 * e1.y + s2 * e1.z + s3 * e1.w;                   \
        A2 += s0 * e2.x + s1 * e2.y + s2 * e2.z + s3 * e2.w;                   \
        A3 += s0 * e3.x + s1 * e3.y + s2 * e3.z + s3 * e3.w;                   \
    }

#define ROW_BODY()                                                             \
    {                                                                          \
        float4 bA = *(const float4*)(xA + HW);                                 \
        float4 bB = *(const float4*)(xB + HW);                                 \
        float4 e0 = *(const float4*)(ep);                                      \
        float4 e1 = *(const float4*)(ep + 4);                                  \
        float4 e2 = *(const float4*)(ep + 8);                                  \
        float4 e3 = *(const float4*)(ep + 12);                                 \
        float teA = __shfl_down(tA.x, 1, 64);                                  \
        float teB = __shfl_down(tB.x, 1, 64);                                  \
        float beA = __shfl_down(bA.x, 1, 64);                                  \
        float beB = __shfl_down(bB.x, 1, 64);                                  \
        CONV4(tA, bA, teA, beA, aA0, aA1, aA2, aA3)                            \
        CONV4(tB, bB, teB, beB, aB0, aB1, aB2, aB3)                            \
        tA = bA; tB = bB;                                                      \
        xA += HW; xB += HW; ep += 56 * 16;                                     \
    }

__global__ __launch_bounds__(256, 4) void conv_embed_stream(
    const float* __restrict__ x, const float* __restrict__ conv_w,
    const float* __restrict__ conv_b, const float* __restrict__ ew_pack,
    float* __restrict__ partial)   // [NCH][NB][4]
{
    const int blk   = blockIdx.x;          // grid = NCH * 128 = 1024
    const int chunk = blk >> 7;            // 0..7
    const int iset  = blk & 127;           // image octet
    const int tid   = threadIdx.x;
    const int wid   = tid >> 6;
    const int lane  = tid & 63;
    const int b     = iset * 8 + wid * 2;  // wave's two images: b, b+1
    const int r0    = chunk * RPC;

    const float w00 = conv_w[0], w01 = conv_w[1];
    const float w10 = conv_w[2], w11 = conv_w[3];
    const float cb  = conv_b[0];

    const int c4 = (lane < 56) ? (lane << 2) : 220;   // clamped col offset

    const float* xA = x + (size_t)b * IMG + (size_t)r0 * HW + c4;
    const float* xB = xA + IMG;
    const float* ep = ew_pack + ((size_t)r0 * 56 + lane) * 16;

    float4 tA = *(const float4*)xA;        // top row of first output row
    float4 tB = *(const float4*)xB;

    float aA0 = 0.f, aA1 = 0.f, aA2 = 0.f, aA3 = 0.f;
    float aB0 = 0.f, aB1 = 0.f, aB2 = 0.f, aB3 = 0.f;

    #pragma unroll 3
    for (int rr = 0; rr < 27; ++rr) ROW_BODY();
    if (chunk != NCH - 1) ROW_BODY();      // chunks 0-6 have 28 rows

    // lanes 56-63 processed clamped/garbage data: drop before reduction
    if (lane >= 56) {
        aA0 = aA1 = aA2 = aA3 = 0.f;
        aB0 = aB1 = aB2 = aB3 = 0.f;
    }

    #pragma unroll
    for (int off = 32; off > 0; off >>= 1) {
        aA0 += __shfl_down(aA0, off, 64);
        aA1 += __shfl_down(aA1, off, 64);
        aA2 += __shfl_down(aA2, off, 64);
        aA3 += __shfl_down(aA3, off, 64);
        aB0 += __shfl_down(aB0, off, 64);
        aB1 += __shfl_down(aB1, off, 64);
        aB2 += __shfl_down(aB2, off, 64);
        aB3 += __shfl_down(aB3, off, 64);
    }
    if (lane == 0) {
        ((float4*)(partial + ((size_t)chunk * NB + b) * 4))[0] =
            make_float4(aA0, aA1, aA2, aA3);
        ((float4*)(partial + ((size_t)chunk * NB + b + 1) * 4))[0] =
            make_float4(aB0, aB1, aB2, aB3);
    }
}

// ---------------------------------------------------------------------------
// Fallback (round-1 style) if ws too small.
// ---------------------------------------------------------------------------
__global__ __launch_bounds__(256) void conv_embed_kernel(
    const float* __restrict__ x, const float* __restrict__ conv_w,
    const float* __restrict__ conv_b, const float* __restrict__ embed_w,
    const float* __restrict__ embed_b, float* __restrict__ embedded)
{
    const int b   = blockIdx.x;
    const int tid = threadIdx.x;
    const float w00 = conv_w[0], w01 = conv_w[1];
    const float w10 = conv_w[2], w11 = conv_w[3];
    const float cb  = conv_b[0];
    const float* __restrict__ xb  = x + (size_t)b * IMG;
    const float* __restrict__ ew0 = embed_w;
    const float* __restrict__ ew1 = embed_w + FLAT;
    const float* __restrict__ ew2 = embed_w + 2 * FLAT;
    const float* __restrict__ ew3 = embed_w + 3 * FLAT;
    float a0 = 0.f, a1 = 0.f, a2 = 0.f, a3 = 0.f;
    for (int p = tid; p < FLAT; p += 256) {
        unsigned up = (unsigned)p;
        unsigned i  = up / 223u;
        unsigned j  = up - i * 223u;
        const float* xr = xb + i * HW + j;
        float z = w00 * xr[0] + w01 * xr[1] + w10 * xr[HW] + w11 * xr[HW + 1] + cb;
        float s = 1.0f / (1.0f + __expf(-z));
        a0 += s * ew0[p]; a1 += s * ew1[p]; a2 += s * ew2[p]; a3 += s * ew3[p];
    }
    #pragma unroll
    for (int off = 32; off > 0; off >>= 1) {
        a0 += __shfl_down(a0, off, 64);
        a1 += __shfl_down(a1, off, 64);
        a2 += __shfl_down(a2, off, 64);
        a3 += __shfl_down(a3, off, 64);
    }
    __shared__ float red[4][4];
    const int wid  = tid >> 6;
    const int lane = tid & 63;
    if (lane == 0) { red[wid][0]=a0; red[wid][1]=a1; red[wid][2]=a2; red[wid][3]=a3; }
    __syncthreads();
    if (tid == 0) {
        float r0 = red[0][0]+red[1][0]+red[2][0]+red[3][0]+embed_b[0];
        float r1 = red[0][1]+red[1][1]+red[2][1]+red[3][1]+embed_b[1];
        float r2 = red[0][2]+red[1][2]+red[2][2]+red[3][2]+embed_b[2];
        float r3 = red[0][3]+red[1][3]+red[2][3]+red[3][3]+embed_b[3];
        ((float4*)(embedded + (size_t)b * 4))[0] = make_float4(r0, r1, r2, r3);
    }
}

// ---------------------------------------------------------------------------
// Kernel 2: sum NCH partials (+bias) -> embedded, then q/k projections
// ---------------------------------------------------------------------------
__global__ __launch_bounds__(256) void qk_reduce_kernel(
    const float* __restrict__ partial, const float* __restrict__ embed_b,
    const float* __restrict__ rot, const float* __restrict__ ent,
    float* __restrict__ embedded, float* __restrict__ q, float* __restrict__ k)
{
    int b = blockIdx.x * 256 + threadIdx.x;
    if (b >= NB) return;
    float r0 = embed_b[0], r1 = embed_b[1], r2 = embed_b[2], r3 = embed_b[3];
    #pragma unroll
    for (int s = 0; s < NCH; ++s) {
        float4 p = ((const float4*)partial)[(size_t)s * NB + b];
        r0 += p.x; r1 += p.y; r2 += p.z; r3 += p.w;
    }
    float4 ev = make_float4(r0, r1, r2, r3);
    ((float4*)embedded)[b] = ev;
    float qv[4], kv[4];
    #pragma unroll
    for (int c = 0; c < 4; ++c) {
        qv[c] = ev.x * rot[0*4+c] + ev.y * rot[1*4+c] + ev.z * rot[2*4+c] + ev.w * rot[3*4+c];
        kv[c] = ev.x * ent[0*4+c] + ev.y * ent[1*4+c] + ev.z * ent[2*4+c] + ev.w * ent[3*4+c];
    }
    ((float4*)q)[b] = make_float4(qv[0], qv[1], qv[2], qv[3]);
    ((float4*)k)[b] = make_float4(kv[0], kv[1], kv[2], kv[3]);
}

__global__ __launch_bounds__(256) void qk_kernel(
    const float* __restrict__ embedded, const float* __restrict__ rot,
    const float* __restrict__ ent, float* __restrict__ q, float* __restrict__ k)
{
    int b = blockIdx.x * 256 + threadIdx.x;
    if (b >= NB) return;
    float4 ev = ((const float4*)embedded)[b];
    float qv[4], kv[4];
    #pragma unroll
    for (int c = 0; c < 4; ++c) {
        qv[c] = ev.x * rot[0*4+c] + ev.y * rot[1*4+c] + ev.z * rot[2*4+c] + ev.w * rot[3*4+c];
        kv[c] = ev.x * ent[0*4+c] + ev.y * ent[1*4+c] + ev.z * ent[2*4+c] + ev.w * ent[3*4+c];
    }
    ((float4*)q)[b] = make_float4(qv[0], qv[1], qv[2], qv[3]);
    ((float4*)k)[b] = make_float4(kv[0], kv[1], kv[2], kv[3]);
}

// ---------------------------------------------------------------------------
// Kernel 3: per-row softmax attention + mean + sigmoid -> out [NB, 2]
// ---------------------------------------------------------------------------
__global__ __launch_bounds__(256) void attn_kernel(
    const float* __restrict__ embedded, const float* __restrict__ q,
    const float* __restrict__ k, float* __restrict__ out)
{
    __shared__ float4 k_lds[NB];
    __shared__ float4 e_lds[NB];
    const int r   = blockIdx.x;
    const int tid = threadIdx.x;

    for (int c = tid; c < NB; c += 256) {
        k_lds[c] = ((const float4*)k)[c];
        e_lds[c] = ((const float4*)embedded)[c];
    }
    __syncthreads();

    const float4 qr = ((const float4*)q)[r];

    float m = -INFINITY, l = 0.f;
    float a0 = 0.f, a1 = 0.f, a2 = 0.f, a3 = 0.f;

    for (int c = tid; c < NB; c += 256) {
        float4 kc = k_lds[c];
        float s = 0.5f * (qr.x * kc.x + qr.y * kc.y + qr.z * kc.z + qr.w * kc.w);
        float mn    = fmaxf(m, s);
        float scale = __expf(m - mn);
        float p     = __expf(s - mn);
        float4 ec = e_lds[c];
        l  = l  * scale + p;
        a0 = a0 * scale + p * ec.x;
        a1 = a1 * scale + p * ec.y;
        a2 = a2 * scale + p * ec.z;
        a3 = a3 * scale + p * ec.w;
        m = mn;
    }

    #pragma unroll
    for (int off = 32; off > 0; off >>= 1) {
        float m2 = __shfl_down(m,  off, 64);
        float l2 = __shfl_down(l,  off, 64);
        float b0 = __shfl_down(a0, off, 64);
        float b1 = __shfl_down(a1, off, 64);
        float b2 = __shfl_down(a2, off, 64);
        float b3 = __shfl_down(a3, off, 64);
        float mn = fmaxf(m, m2);
        float s1 = __expf(m - mn), s2 = __expf(m2 - mn);
        l  = l  * s1 + l2 * s2;
        a0 = a0 * s1 + b0 * s2;
        a1 = a1 * s1 + b1 * s2;
        a2 = a2 * s1 + b2 * s2;
        a3 = a3 * s1 + b3 * s2;
        m = mn;
    }

    __shared__ float wred[4][6];
    const int wid  = tid >> 6;
    const int lane = tid & 63;
    if (lane == 0) {
        wred[wid][0] = m;  wred[wid][1] = l;
        wred[wid][2] = a0; wred[wid][3] = a1;
        wred[wid][4] = a2; wred[wid][5] = a3;
    }
    __syncthreads();
    if (tid == 0) {
        float M = wred[0][0], L = wred[0][1];
        float A0 = wred[0][2], A1 = wred[0][3], A2 = wred[0][4], A3 = wred[0][5];
        #pragma unroll
        for (int w = 1; w < 4; ++w) {
            float m2 = wred[w][0];
            float mn = fmaxf(M, m2);
            float s1 = __expf(M - mn), s2 = __expf(m2 - mn);
            L  = L  * s1 + wred[w][1] * s2;
            A0 = A0 * s1 + wred[w][2] * s2;
            A1 = A1 * s1 + wred[w][3] * s2;
            A2 = A2 * s1 + wred[w][4] * s2;
            A3 = A3 * s1 + wred[w][5] * s2;
            M = mn;
        }
        float mean = (A0 + A1 + A2 + A3) / (4.0f * L);
        float prob = 1.0f / (1.0f + __expf(-mean));
        out[r * 2 + 0] = prob;
        out[r * 2 + 1] = 1.0f - prob;
    }
}

// ---------------------------------------------------------------------------
extern "C" void kernel_launch(void* const* d_in, const int* in_sizes, int n_in,
                              void* d_out, int out_size, void* d_ws, size_t ws_size,
                              hipStream_t stream) {
    const float* x       = (const float*)d_in[0];
    const float* conv_w  = (const float*)d_in[1];
    const float* conv_b  = (const float*)d_in[2];
    const float* embed_w = (const float*)d_in[3];
    const float* embed_b = (const float*)d_in[4];
    const float* rot     = (const float*)d_in[5];
    const float* ent     = (const float*)d_in[6];
    float* out = (float*)d_out;

    float* partial  = (float*)d_ws;                 // NCH*NB*4 floats
    float* embedded = partial + NCH * NB * 4;       // NB*4
    float* q        = embedded + NB * 4;            // NB*4
    float* k        = q + NB * 4;                   // NB*4
    float* ew_pack  = k + NB * 4;                   // EWPK floats (+slack)

    // slack: lanes 56-63 at the last row read up to 128 floats past EWPK
    const size_t need = (size_t)(NCH * NB * 4 + NB * 12 + EWPK + 1024) * sizeof(float);

    if (ws_size >= need) {
        pack_ew_kernel<<<(NGRP * 4 + 255) / 256, 256, 0, stream>>>(embed_w, ew_pack);
        conv_embed_stream<<<NCH * 128, 256, 0, stream>>>(x, conv_w, conv_b,
                                                         ew_pack, partial);
        qk_reduce_kernel<<<NB / 256, 256, 0, stream>>>(partial, embed_b, rot, ent,
                                                       embedded, q, k);
    } else {
        conv_embed_kernel<<<NB, 256, 0, stream>>>(x, conv_w, conv_b, embed_w,
                                                  embed_b, embedded);
        qk_kernel<<<NB / 256, 256, 0, stream>>>(embedded, rot, ent, q, k);
    }
    attn_kernel<<<NB, 256, 0, stream>>>(embedded, q, k, out);
}